// Round 10
// baseline (3493.975 us; speedup 1.0000x reference)
//
#include <hip/hip_runtime.h>
#include <hip/hip_fp16.h>

#define BB 4096
#define NN 4096
#define RPB 4            // rows per block in k_K
#define RPI 8            // rows per block in k_it / k_sink / k_P
#define NBLK (BB / RPI)  // 512 row-blocks
#define NBAR 20          // global barriers in k_sink
#define NGRP 16          // arrival sub-counter groups
#define CNT_INTS (NBAR * NGRP * 32)
#define MST_INTS (NBAR * 32)
#define BAR_INTS (CNT_INTS + MST_INTS + 32)   // + flag line

// XCD-contiguous swizzle for the fallback path
__device__ __forceinline__ int swz(int bid) { return (bid & 7) * 64 + (bid >> 3); }

// ---------------- mean(D) reduction + v=1 init (v init used by fallback) ----
__global__ __launch_bounds__(256) void k_mean(
        const float* __restrict__ Dt, float* __restrict__ dsum,
        float* __restrict__ v) {
    const int tid = blockIdx.x * blockDim.x + threadIdx.x;
    const int gs = gridDim.x * blockDim.x;
    if (tid < NN) v[tid] = 1.0f;
    const float4* D4 = (const float4*)Dt;
    const int total4 = (BB * NN) / 4;
    float s = 0.f;
    for (int i = tid; i < total4; i += gs) {
        float4 d = D4[i];
        s += (d.x + d.y) + (d.z + d.w);
    }
    #pragma unroll
    for (int off = 32; off > 0; off >>= 1) s += __shfl_down(s, off, 64);
    __shared__ float ls[4];
    if ((threadIdx.x & 63) == 0) ls[threadIdx.x >> 6] = s;
    __syncthreads();
    if (threadIdx.x == 0) atomicAdd(dsum, (ls[0] + ls[1]) + (ls[2] + ls[3]));
}

// ---------------- K = exp(5*dot - 5*D/mean), fp16, fp16 lut ----------------
// (round-6 measured-best version: RPB=4, ue in VGPRs)
__global__ __launch_bounds__(256) void k_K(
        const int* __restrict__ users, const int* __restrict__ pois,
        const float* __restrict__ Dt, const float* __restrict__ poi_emb,
        const float* __restrict__ user_emb, const float* __restrict__ dsum,
        __half* __restrict__ K) {
    __shared__ __half slut[RPB][NN];      // 32 KB
    __shared__ float ues[RPB * 16];
    const int t = threadIdx.x;
    const int b0 = blockIdx.x * RPB;
    if (t < RPB * 16) {
        int r = t >> 4, d = t & 15;
        ues[t] = user_emb[(size_t)users[b0 + r] * 16 + d];
    }
    __syncthreads();
    float ue[RPB][16];
    #pragma unroll
    for (int r = 0; r < RPB; r++)
        #pragma unroll
        for (int d = 0; d < 16; d++) ue[r][d] = ues[r * 16 + d];

    const float4* pe4 = (const float4*)poi_emb;
    for (int j = t; j < NN; j += 256) {
        float4 p0 = pe4[j * 4 + 0];
        float4 p1 = pe4[j * 4 + 1];
        float4 p2 = pe4[j * 4 + 2];
        float4 p3 = pe4[j * 4 + 3];
        #pragma unroll
        for (int r = 0; r < RPB; r++) {
            float acc = p0.x*ue[r][0]  + p0.y*ue[r][1]  + p0.z*ue[r][2]  + p0.w*ue[r][3]
                      + p1.x*ue[r][4]  + p1.y*ue[r][5]  + p1.z*ue[r][6]  + p1.w*ue[r][7]
                      + p2.x*ue[r][8]  + p2.y*ue[r][9]  + p2.z*ue[r][10] + p2.w*ue[r][11]
                      + p3.x*ue[r][12] + p3.y*ue[r][13] + p3.z*ue[r][14] + p3.w*ue[r][15];
            slut[r][j] = __float2half(acc);
        }
    }
    __syncthreads();                       // lut read-only from here on
    const float cc = 5.0f * 16777216.0f / dsum[0];   // 5 / mean(D)
    #pragma unroll
    for (int r = 0; r < RPB; r++) {
        const size_t base = (size_t)(b0 + r) * NN;
        const int4*   p4 = (const int4*)(pois + base);
        const float4* d4 = (const float4*)(Dt + base);
        #pragma unroll
        for (int i = 0; i < NN / 4 / 256; i++) {     // 4
            const int q = t + i * 256;
            int4   ci = p4[q];
            float4 cd = d4[q];
            float k0 = __expf(5.0f * __half2float(slut[r][ci.x]) - cc * cd.x);
            float k1 = __expf(5.0f * __half2float(slut[r][ci.y]) - cc * cd.y);
            float k2 = __expf(5.0f * __half2float(slut[r][ci.z]) - cc * cd.z);
            float k3 = __expf(5.0f * __half2float(slut[r][ci.w]) - cc * cd.w);
            __half2* kw = (__half2*)&K[base + 4 * (size_t)q];
            kw[0] = __floats2half2_rn(k0, k1);
            kw[1] = __floats2half2_rn(k2, k3);
        }
    }
}

// ================= persistent sinkhorn (cooperative, fixed barrier) ========
// Storm-free global barrier:
//  - arrivals: 16 spread sub-counter lines (32 RMWs each), last per group
//    bumps a master counter; the 16th master-bump stores flag = k+1 (release).
//  - waiters: poll the write-once flag line with s_sleep(64) (~4K cy) backoff
//    -> 512 pollers = ~0.125 polls/cy at L3, no queueing storm.
__device__ __forceinline__ void gbar(int k, int* cnt, int* mst, int* flag) {
    __threadfence();                                   // release block's writes
    __syncthreads();
    if (threadIdx.x == 0) {
        int* c = cnt + (k * NGRP + (blockIdx.x & (NGRP - 1))) * 32;
        int old = __hip_atomic_fetch_add(c, 1, __ATOMIC_ACQ_REL,
                                         __HIP_MEMORY_SCOPE_AGENT);
        if (old == NBLK / NGRP - 1) {
            int m = __hip_atomic_fetch_add(mst + k * 32, 1, __ATOMIC_ACQ_REL,
                                           __HIP_MEMORY_SCOPE_AGENT);
            if (m == NGRP - 1)
                __hip_atomic_store(flag, k + 1, __ATOMIC_RELEASE,
                                   __HIP_MEMORY_SCOPE_AGENT);
        }
        while (__hip_atomic_load(flag, __ATOMIC_ACQUIRE,
                                 __HIP_MEMORY_SCOPE_AGENT) < k + 1)
            __builtin_amdgcn_s_sleep(64);
    }
    __syncthreads();
    __builtin_amdgcn_fence(__ATOMIC_ACQUIRE, "agent");
}

// Block sb owns rows [8sb, 8sb+8): K fragments live in registers the whole
// kernel (thread t holds cols [8t,8t+8) of each row = 32 VGPR). Per iter:
// u (block-local), partials -> part[sb][:], barrier, reduce stripe sb -> v,
// barrier. After 10 iters: P = u*K*v written straight from registers.
__global__ __launch_bounds__(512, 4) void k_sink(
        const __half* __restrict__ K, const float* __restrict__ cap,
        float* part, float* __restrict__ v, float* P,
        int* __restrict__ bcnt, int* __restrict__ bmst,
        int* __restrict__ bflag) {
    const int t = threadIdx.x;
    const int sb = blockIdx.x;
    const int r0 = sb * RPI;

    float4 h[RPI];
    #pragma unroll
    for (int r = 0; r < RPI; r++)
        h[r] = ((const float4*)(K + (size_t)(r0 + r) * NN))[t];

    __shared__ float ls[8][RPI];
    __shared__ float us[RPI];
    __shared__ float ls2[8][8];

    #pragma unroll 1
    for (int it = 0; it < 10; it++) {
        float4 w0, w1;
        if (it == 0) { w0 = make_float4(1.f, 1.f, 1.f, 1.f); w1 = w0; }
        else { w0 = ((const float4*)v)[2 * t]; w1 = ((const float4*)v)[2 * t + 1]; }

        // ---- u[r] = 1 / (K[r,:].v) for the block's 8 rows ----
        float acc[RPI];
        #pragma unroll
        for (int r = 0; r < RPI; r++) {
            const __half2* a = (const __half2*)&h[r];
            float2 f; float s = 0.f;
            f = __half22float2(a[0]); s += f.x * w0.x + f.y * w0.y;
            f = __half22float2(a[1]); s += f.x * w0.z + f.y * w0.w;
            f = __half22float2(a[2]); s += f.x * w1.x + f.y * w1.y;
            f = __half22float2(a[3]); s += f.x * w1.z + f.y * w1.w;
            acc[r] = s;
        }
        #pragma unroll
        for (int off = 32; off > 0; off >>= 1)
            #pragma unroll
            for (int r = 0; r < RPI; r++) acc[r] += __shfl_down(acc[r], off, 64);
        __syncthreads();                 // ls reused across iterations
        if ((t & 63) == 0)
            #pragma unroll
            for (int r = 0; r < RPI; r++) ls[t >> 6][r] = acc[r];
        __syncthreads();
        if (t < RPI) {
            float s = 0.f;
            #pragma unroll
            for (int wv = 0; wv < 8; wv++) s += ls[wv][t];
            us[t] = 1.0f / s;
        }
        __syncthreads();

        // ---- column partials for this block's rows ----
        float4 A0 = make_float4(0, 0, 0, 0), A1 = A0;
        #pragma unroll
        for (int r = 0; r < RPI; r++) {
            const float ur = us[r];
            const __half2* a = (const __half2*)&h[r];
            float2 f;
            f = __half22float2(a[0]); A0.x += ur * f.x; A0.y += ur * f.y;
            f = __half22float2(a[1]); A0.z += ur * f.x; A0.w += ur * f.y;
            f = __half22float2(a[2]); A1.x += ur * f.x; A1.y += ur * f.y;
            f = __half22float2(a[3]); A1.z += ur * f.x; A1.w += ur * f.y;
        }
        ((float4*)part)[(size_t)sb * 1024 + 2 * t]     = A0;
        ((float4*)part)[(size_t)sb * 1024 + 2 * t + 1] = A1;

        gbar(2 * it, bcnt, bmst, bflag);   // all partials visible

        // ---- reduce stripe sb: v[8sb+j] = cap/sum_slices part[s][8sb+j] ----
        float4 pa = ((const float4*)part)[(size_t)t * 1024 + 2 * sb];
        float4 pb = ((const float4*)part)[(size_t)t * 1024 + 2 * sb + 1];
        #pragma unroll
        for (int off = 32; off > 0; off >>= 1) {
            pa.x += __shfl_down(pa.x, off, 64); pa.y += __shfl_down(pa.y, off, 64);
            pa.z += __shfl_down(pa.z, off, 64); pa.w += __shfl_down(pa.w, off, 64);
            pb.x += __shfl_down(pb.x, off, 64); pb.y += __shfl_down(pb.y, off, 64);
            pb.z += __shfl_down(pb.z, off, 64); pb.w += __shfl_down(pb.w, off, 64);
        }
        __syncthreads();                 // ls2 reused across iterations
        if ((t & 63) == 0) {
            const int wv = t >> 6;
            ls2[wv][0] = pa.x; ls2[wv][1] = pa.y; ls2[wv][2] = pa.z; ls2[wv][3] = pa.w;
            ls2[wv][4] = pb.x; ls2[wv][5] = pb.y; ls2[wv][6] = pb.z; ls2[wv][7] = pb.w;
        }
        __syncthreads();
        if (t < 8) {
            float s = 0.f;
            #pragma unroll
            for (int wv = 0; wv < 8; wv++) s += ls2[wv][t];
            v[8 * sb + t] = cap[8 * sb + t] / s;
        }

        gbar(2 * it + 1, bcnt, bmst, bflag);   // v fully visible
    }

    // ---- P = K * u[b] * v[n], straight from registers ----
    float4 w0 = ((const float4*)v)[2 * t], w1 = ((const float4*)v)[2 * t + 1];
    #pragma unroll
    for (int r = 0; r < RPI; r++) {
        const float ur = us[r];
        const __half2* a = (const __half2*)&h[r];
        float2 f0 = __half22float2(a[0]);
        float2 f1 = __half22float2(a[1]);
        float2 f2 = __half22float2(a[2]);
        float2 f3 = __half22float2(a[3]);
        float4* P4 = (float4*)(P + (size_t)(r0 + r) * NN);
        P4[2 * t]     = make_float4(f0.x*ur*w0.x, f0.y*ur*w0.y, f1.x*ur*w0.z, f1.y*ur*w0.w);
        P4[2 * t + 1] = make_float4(f2.x*ur*w1.x, f2.y*ur*w1.y, f3.x*ur*w1.z, f3.y*ur*w1.w);
    }
}

// ================= fallback path (round-6 proven, 386 us) ==================
__global__ __launch_bounds__(512) void k_it(
        const __half* __restrict__ K, const float* __restrict__ v,
        float* __restrict__ part, float* __restrict__ u) {
    const int t = threadIdx.x;
    const int sb = swz(blockIdx.x);
    const int r0 = sb * RPI;
    const float4* w4 = (const float4*)v;
    float4 w0 = w4[2 * t], w1 = w4[2 * t + 1];
    float4 h[RPI];
    #pragma unroll
    for (int r = 0; r < RPI; r++)
        h[r] = ((const float4*)(K + (size_t)(r0 + r) * NN))[t];
    float acc[RPI];
    #pragma unroll
    for (int r = 0; r < RPI; r++) {
        const __half2* a = (const __half2*)&h[r];
        float2 f; float s = 0.f;
        f = __half22float2(a[0]); s += f.x * w0.x + f.y * w0.y;
        f = __half22float2(a[1]); s += f.x * w0.z + f.y * w0.w;
        f = __half22float2(a[2]); s += f.x * w1.x + f.y * w1.y;
        f = __half22float2(a[3]); s += f.x * w1.z + f.y * w1.w;
        acc[r] = s;
    }
    #pragma unroll
    for (int off = 32; off > 0; off >>= 1)
        #pragma unroll
        for (int r = 0; r < RPI; r++) acc[r] += __shfl_down(acc[r], off, 64);
    __shared__ float ls[8][RPI];
    __shared__ float us[RPI];
    if ((t & 63) == 0)
        #pragma unroll
        for (int r = 0; r < RPI; r++) ls[t >> 6][r] = acc[r];
    __syncthreads();
    if (t < RPI) {
        float s = 0.f;
        #pragma unroll
        for (int wv = 0; wv < 8; wv++) s += ls[wv][t];
        float uu = 1.0f / s;
        us[t] = uu;
        u[r0 + t] = uu;
    }
    __syncthreads();
    float4 A0 = make_float4(0, 0, 0, 0), A1 = A0;
    #pragma unroll
    for (int r = 0; r < RPI; r++) {
        const float ur = us[r];
        const __half2* a = (const __half2*)&h[r];
        float2 f;
        f = __half22float2(a[0]); A0.x += ur * f.x; A0.y += ur * f.y;
        f = __half22float2(a[1]); A0.z += ur * f.x; A0.w += ur * f.y;
        f = __half22float2(a[2]); A1.x += ur * f.x; A1.y += ur * f.y;
        f = __half22float2(a[3]); A1.z += ur * f.x; A1.w += ur * f.y;
    }
    float4* p4 = (float4*)(part + (size_t)sb * NN);
    p4[2 * t]     = A0;
    p4[2 * t + 1] = A1;
}

__global__ __launch_bounds__(256) void k_red(
        const float* __restrict__ part, const float* __restrict__ cap,
        float* __restrict__ v) {
    const int t = threadIdx.x;
    const int g = blockIdx.x;
    const int j = t & 7;
    const int s = t >> 3;
    const float4* p4 = (const float4*)part;
    float4 a = make_float4(0, 0, 0, 0);
    #pragma unroll
    for (int i = 0; i < NBLK / 32; i++) {
        float4 x = p4[(size_t)(s + 32 * i) * (NN / 4) + g * 8 + j];
        a.x += x.x; a.y += x.y; a.z += x.z; a.w += x.w;
    }
    __shared__ float4 red[32][8];
    red[s][j] = a;
    __syncthreads();
    if (t < 8) {
        float4 b = red[0][t];
        #pragma unroll
        for (int s2 = 1; s2 < 32; s2++) {
            float4 x = red[s2][t];
            b.x += x.x; b.y += x.y; b.z += x.z; b.w += x.w;
        }
        float4 cc = ((const float4*)cap)[g * 8 + t];
        ((float4*)v)[g * 8 + t] =
            make_float4(cc.x / b.x, cc.y / b.y, cc.z / b.z, cc.w / b.w);
    }
}

__global__ __launch_bounds__(256) void k_P(
        const __half* __restrict__ K, const float* __restrict__ u,
        const float* __restrict__ v, float* __restrict__ P) {
    const int t = threadIdx.x;
    const int sb = swz(blockIdx.x);
    const int r0 = sb * RPI;
    const float4* v4 = (const float4*)v;
    float4 va0 = v4[2 * t],       va1 = v4[2 * t + 1];
    float4 vb0 = v4[512 + 2 * t], vb1 = v4[512 + 2 * t + 1];
    #pragma unroll 2
    for (int r = 0; r < RPI; r++) {
        const int b = r0 + r;
        const float ub = u[b];
        const size_t base = (size_t)b * NN;
        const float4* k4 = (const float4*)(K + base);
        float4 raw0 = k4[t], raw1 = k4[256 + t];
        const __half2* ha = (const __half2*)&raw0;
        const __half2* hb = (const __half2*)&raw1;
        float2 f0 = __half22float2(ha[0]);
        float2 f1 = __half22float2(ha[1]);
        float2 f2 = __half22float2(ha[2]);
        float2 f3 = __half22float2(ha[3]);
        float2 g0 = __half22float2(hb[0]);
        float2 g1 = __half22float2(hb[1]);
        float2 g2 = __half22float2(hb[2]);
        float2 g3 = __half22float2(hb[3]);
        float4* P4 = (float4*)(P + base);
        P4[2*t]       = make_float4(f0.x*ub*va0.x, f0.y*ub*va0.y, f1.x*ub*va0.z, f1.y*ub*va0.w);
        P4[2*t+1]     = make_float4(f2.x*ub*va1.x, f2.y*ub*va1.y, f3.x*ub*va1.z, f3.y*ub*va1.w);
        P4[512+2*t]   = make_float4(g0.x*ub*vb0.x, g0.y*ub*vb0.y, g1.x*ub*vb0.z, g1.y*ub*vb0.w);
        P4[512+2*t+1] = make_float4(g2.x*ub*vb1.x, g2.y*ub*vb1.y, g3.x*ub*vb1.z, g3.y*ub*vb1.w);
    }
}

extern "C" void kernel_launch(void* const* d_in, const int* in_sizes, int n_in,
                              void* d_out, int out_size, void* d_ws, size_t ws_size,
                              hipStream_t stream) {
    const int*   users    = (const int*)d_in[0];
    const int*   pois     = (const int*)d_in[1];
    const float* Dt       = (const float*)d_in[2];
    const float* poi_emb  = (const float*)d_in[3];
    const float* user_emb = (const float*)d_in[4];
    const float* cap      = (const float*)d_in[5];
    float* out = (float*)d_out;

    float*  wsf  = (float*)d_ws;
    float*  dsum = wsf;                         // [64]
    int*    bcnt = (int*)(wsf + 64);            // [CNT_INTS]
    int*    bmst = bcnt + CNT_INTS;             // [MST_INTS]
    int*    bflag= bmst + MST_INTS;             // [32]
    float*  v    = wsf + 64 + BAR_INTS;         // [NN]
    float*  u    = v + NN;                      // [BB] (fallback only)
    __half* Kh   = (__half*)(u + BB);           // [BB*NN] fp16 = 33.5 MB
    float*  part = (float*)d_out;               // [NBLK*NN] = 8 MB; dead before P

    (void)hipMemsetAsync(wsf, 0, (64 + BAR_INTS) * sizeof(float), stream);
    k_mean<<<2048, 256, 0, stream>>>(Dt, dsum, v);
    k_K<<<BB / RPB, 256, 0, stream>>>(users, pois, Dt, poi_emb, user_emb, dsum, Kh);

    const __half* Kh_c = Kh;
    const float* cap_c = cap;
    float* part_p = part;
    float* v_p = v;
    float* out_p = out;
    int* bcnt_p = bcnt;
    int* bmst_p = bmst;
    int* bflag_p = bflag;
    void* args[] = { &Kh_c, &cap_c, &part_p, &v_p, &out_p,
                     &bcnt_p, &bmst_p, &bflag_p };
    hipError_t cerr = hipLaunchCooperativeKernel(
        reinterpret_cast<const void*>(&k_sink),
        dim3(NBLK), dim3(512), args, 0, stream);
    if (cerr != hipSuccess) {
        for (int it = 0; it < 10; it++) {
            k_it<<<NBLK, 512, 0, stream>>>(Kh, v, part, u);
            k_red<<<128, 256, 0, stream>>>(part, cap, v);
        }
        k_P<<<NBLK, 256, 0, stream>>>(Kh, u, v, out);
    }
}

// Round 11
// 558.703 us; speedup vs baseline: 6.2537x; 6.2537x over previous
//
#include <hip/hip_runtime.h>
#include <hip/hip_fp16.h>

#define BB 4096
#define NN 4096
#define RPB 4            // rows per block in k_K
#define IBLK 64          // blocks in k_it (8 per XCD)
#define IROW (BB / IBLK) // 64 rows per k_it block
#define ICH 8            // rows per chunk in k_it
#define NSL IBLK         // partial slices
#define RPP 8            // rows per block in k_P
#define PBLK (BB / RPP)  // 512 blocks in k_P

// XCD-contiguous swizzles (round-robin dispatch: bid%8 -> XCD bid%8).
// XCD x owns rows [512x, 512x+512) = one 4 MiB fp16 K panel in all kernels.
__device__ __forceinline__ int swzK(int bid) { return (bid & 7) * 128 + (bid >> 3); } // 1024 blk
__device__ __forceinline__ int swzI(int bid) { return (bid & 7) * 8   + (bid >> 3); } // 64 blk
__device__ __forceinline__ int swzP(int bid) { return (bid & 7) * 64  + (bid >> 3); } // 512 blk

// ---------------- mean(D) reduction + partial-buffer init ----------------
// partA slice 0 = cap, slices 1..63 = 0  =>  first k_it derives v0 = 1 exactly.
__global__ __launch_bounds__(256) void k_mean(
        const float* __restrict__ Dt, float* __restrict__ dsum,
        float* __restrict__ partA, const float* __restrict__ cap) {
    const int tid = blockIdx.x * blockDim.x + threadIdx.x;
    const int gs = gridDim.x * blockDim.x;
    for (int i = tid; i < NSL * NN; i += gs)
        partA[i] = (i < NN) ? cap[i] : 0.f;
    const float4* D4 = (const float4*)Dt;
    const int total4 = (BB * NN) / 4;
    float s = 0.f;
    for (int i = tid; i < total4; i += gs) {
        float4 d = D4[i];
        s += (d.x + d.y) + (d.z + d.w);
    }
    #pragma unroll
    for (int off = 32; off > 0; off >>= 1) s += __shfl_down(s, off, 64);
    __shared__ float ls[4];
    if ((threadIdx.x & 63) == 0) ls[threadIdx.x >> 6] = s;
    __syncthreads();
    if (threadIdx.x == 0) atomicAdd(dsum, (ls[0] + ls[1]) + (ls[2] + ls[3]));
}

// ---------------- K = exp(5*dot - 5*D/mean), fp16, fp16 lut ----------------
// Round-6 structure (measured best) + XCD-aligned row swizzle: each XCD
// writes its own future K panel -> panel is L2-local for k_it/k_P.
__global__ __launch_bounds__(256) void k_K(
        const int* __restrict__ users, const int* __restrict__ pois,
        const float* __restrict__ Dt, const float* __restrict__ poi_emb,
        const float* __restrict__ user_emb, const float* __restrict__ dsum,
        __half* __restrict__ K) {
    __shared__ __half slut[RPB][NN];      // 32 KB
    __shared__ float ues[RPB * 16];
    const int t = threadIdx.x;
    const int b0 = swzK(blockIdx.x) * RPB;
    if (t < RPB * 16) {
        int r = t >> 4, d = t & 15;
        ues[t] = user_emb[(size_t)users[b0 + r] * 16 + d];
    }
    __syncthreads();
    float ue[RPB][16];
    #pragma unroll
    for (int r = 0; r < RPB; r++)
        #pragma unroll
        for (int d = 0; d < 16; d++) ue[r][d] = ues[r * 16 + d];

    const float4* pe4 = (const float4*)poi_emb;
    for (int j = t; j < NN; j += 256) {
        float4 p0 = pe4[j * 4 + 0];
        float4 p1 = pe4[j * 4 + 1];
        float4 p2 = pe4[j * 4 + 2];
        float4 p3 = pe4[j * 4 + 3];
        #pragma unroll
        for (int r = 0; r < RPB; r++) {
            float acc = p0.x*ue[r][0]  + p0.y*ue[r][1]  + p0.z*ue[r][2]  + p0.w*ue[r][3]
                      + p1.x*ue[r][4]  + p1.y*ue[r][5]  + p1.z*ue[r][6]  + p1.w*ue[r][7]
                      + p2.x*ue[r][8]  + p2.y*ue[r][9]  + p2.z*ue[r][10] + p2.w*ue[r][11]
                      + p3.x*ue[r][12] + p3.y*ue[r][13] + p3.z*ue[r][14] + p3.w*ue[r][15];
            slut[r][j] = __float2half(acc);
        }
    }
    __syncthreads();                       // lut read-only from here on
    const float cc = 5.0f * 16777216.0f / dsum[0];   // 5 / mean(D)
    #pragma unroll
    for (int r = 0; r < RPB; r++) {
        const size_t base = (size_t)(b0 + r) * NN;
        const int4*   p4 = (const int4*)(pois + base);
        const float4* d4 = (const float4*)(Dt + base);
        #pragma unroll
        for (int i = 0; i < NN / 4 / 256; i++) {     // 4
            const int q = t + i * 256;
            int4   ci = p4[q];
            float4 cd = d4[q];
            float k0 = __expf(5.0f * __half2float(slut[r][ci.x]) - cc * cd.x);
            float k1 = __expf(5.0f * __half2float(slut[r][ci.y]) - cc * cd.y);
            float k2 = __expf(5.0f * __half2float(slut[r][ci.z]) - cc * cd.z);
            float k3 = __expf(5.0f * __half2float(slut[r][ci.w]) - cc * cd.w);
            __half2* kw = (__half2*)&K[base + 4 * (size_t)q];
            kw[0] = __floats2half2_rn(k0, k1);
            kw[1] = __floats2half2_rn(k2, k3);
        }
    }
}

// ---------------- merged sinkhorn iteration: one launch per iteration -----
// Each block: (1) redundantly reduce partIn -> v at its threads' 8 columns
// (thread t only ever needs v[8t..8t+8) for its dot partials); (2) for its
// 64 rows in chunks of 8: u = 1/(K.v), accumulate column partials; (3) write
// its slice to partOut. partIn != partOut (double buffer) -> no intra-launch
// race; launch boundary orders iterations.
__global__ __launch_bounds__(512) void k_it(
        const __half* __restrict__ K, const float* __restrict__ cap,
        const float* __restrict__ partIn, float* __restrict__ partOut,
        float* __restrict__ u) {
    const int t = threadIdx.x;            // 0..511
    const int sb = swzI(blockIdx.x);
    const int r0 = sb * IROW;

    // ---- v at cols [8t, 8t+8): reduce 64 slices (identical in all blocks) --
    const float4* p4 = (const float4*)partIn;
    float4 d0 = make_float4(0, 0, 0, 0), d1 = d0;
    #pragma unroll 8
    for (int s = 0; s < NSL; s++) {
        float4 x0 = p4[s * (NN / 4) + 2 * t];
        float4 x1 = p4[s * (NN / 4) + 2 * t + 1];
        d0.x += x0.x; d0.y += x0.y; d0.z += x0.z; d0.w += x0.w;
        d1.x += x1.x; d1.y += x1.y; d1.z += x1.z; d1.w += x1.w;
    }
    float4 c0 = ((const float4*)cap)[2 * t], c1 = ((const float4*)cap)[2 * t + 1];
    float4 w0 = make_float4(c0.x / d0.x, c0.y / d0.y, c0.z / d0.z, c0.w / d0.w);
    float4 w1 = make_float4(c1.x / d1.x, c1.y / d1.y, c1.z / d1.z, c1.w / d1.w);

    __shared__ float ls[8][ICH];
    __shared__ float us[ICH];
    float4 A0 = make_float4(0, 0, 0, 0), A1 = A0;

    #pragma unroll 1
    for (int ch = 0; ch < IROW / ICH; ch++) {        // 8 chunks of 8 rows
        const int rr = r0 + ch * ICH;
        float4 h[ICH];
        #pragma unroll
        for (int r = 0; r < ICH; r++)
            h[r] = ((const float4*)(K + (size_t)(rr + r) * NN))[t];
        float acc[ICH];
        #pragma unroll
        for (int r = 0; r < ICH; r++) {
            const __half2* a = (const __half2*)&h[r];
            float2 f; float s = 0.f;
            f = __half22float2(a[0]); s += f.x * w0.x + f.y * w0.y;
            f = __half22float2(a[1]); s += f.x * w0.z + f.y * w0.w;
            f = __half22float2(a[2]); s += f.x * w1.x + f.y * w1.y;
            f = __half22float2(a[3]); s += f.x * w1.z + f.y * w1.w;
            acc[r] = s;
        }
        #pragma unroll
        for (int off = 32; off > 0; off >>= 1)
            #pragma unroll
            for (int r = 0; r < ICH; r++) acc[r] += __shfl_down(acc[r], off, 64);
        __syncthreads();                 // ls/us safe for reuse
        if ((t & 63) == 0)
            #pragma unroll
            for (int r = 0; r < ICH; r++) ls[t >> 6][r] = acc[r];
        __syncthreads();
        if (t < ICH) {
            float s = 0.f;
            #pragma unroll
            for (int wv = 0; wv < 8; wv++) s += ls[wv][t];
            float uu = 1.0f / s;
            us[t] = uu;
            u[rr + t] = uu;
        }
        __syncthreads();
        #pragma unroll
        for (int r = 0; r < ICH; r++) {
            const float ur = us[r];
            const __half2* a = (const __half2*)&h[r];
            float2 f;
            f = __half22float2(a[0]); A0.x += ur * f.x; A0.y += ur * f.y;
            f = __half22float2(a[1]); A0.z += ur * f.x; A0.w += ur * f.y;
            f = __half22float2(a[2]); A1.x += ur * f.x; A1.y += ur * f.y;
            f = __half22float2(a[3]); A1.z += ur * f.x; A1.w += ur * f.y;
        }
    }
    float4* o4 = (float4*)partOut + (size_t)sb * (NN / 4);
    o4[2 * t]     = A0;
    o4[2 * t + 1] = A1;
}

// ---------------- v10 = cap / sum_s part[s][n] (final reduce) ----------------
__global__ __launch_bounds__(512) void k_fin(
        const float* __restrict__ part, const float* __restrict__ cap,
        float* __restrict__ v) {
    const int c = blockIdx.x * 512 + threadIdx.x;    // 0..4095
    float s = 0.f;
    #pragma unroll 8
    for (int sl = 0; sl < NSL; sl++) s += part[sl * NN + c];
    v[c] = cap[c] / s;
}

// ---------------- P = K * u[b] * v[n] (round-6 proven) ----------------
__global__ __launch_bounds__(256) void k_P(
        const __half* __restrict__ K, const float* __restrict__ u,
        const float* __restrict__ v, float* __restrict__ P) {
    const int t = threadIdx.x;
    const int sb = swzP(blockIdx.x);
    const int r0 = sb * RPP;
    const float4* v4 = (const float4*)v;
    float4 va0 = v4[2 * t],       va1 = v4[2 * t + 1];
    float4 vb0 = v4[512 + 2 * t], vb1 = v4[512 + 2 * t + 1];
    #pragma unroll 2
    for (int r = 0; r < RPP; r++) {
        const int b = r0 + r;
        const float ub = u[b];
        const size_t base = (size_t)b * NN;
        const float4* k4 = (const float4*)(K + base);
        float4 raw0 = k4[t], raw1 = k4[256 + t];
        const __half2* ha = (const __half2*)&raw0;
        const __half2* hb = (const __half2*)&raw1;
        float2 f0 = __half22float2(ha[0]);
        float2 f1 = __half22float2(ha[1]);
        float2 f2 = __half22float2(ha[2]);
        float2 f3 = __half22float2(ha[3]);
        float2 g0 = __half22float2(hb[0]);
        float2 g1 = __half22float2(hb[1]);
        float2 g2 = __half22float2(hb[2]);
        float2 g3 = __half22float2(hb[3]);
        float4* P4 = (float4*)(P + base);
        P4[2*t]       = make_float4(f0.x*ub*va0.x, f0.y*ub*va0.y, f1.x*ub*va0.z, f1.y*ub*va0.w);
        P4[2*t+1]     = make_float4(f2.x*ub*va1.x, f2.y*ub*va1.y, f3.x*ub*va1.z, f3.y*ub*va1.w);
        P4[512+2*t]   = make_float4(g0.x*ub*vb0.x, g0.y*ub*vb0.y, g1.x*ub*vb0.z, g1.y*ub*vb0.w);
        P4[512+2*t+1] = make_float4(g2.x*ub*vb1.x, g2.y*ub*vb1.y, g3.x*ub*vb1.z, g3.y*ub*vb1.w);
    }
}

extern "C" void kernel_launch(void* const* d_in, const int* in_sizes, int n_in,
                              void* d_out, int out_size, void* d_ws, size_t ws_size,
                              hipStream_t stream) {
    const int*   users    = (const int*)d_in[0];
    const int*   pois     = (const int*)d_in[1];
    const float* Dt       = (const float*)d_in[2];
    const float* poi_emb  = (const float*)d_in[3];
    const float* user_emb = (const float*)d_in[4];
    const float* cap      = (const float*)d_in[5];
    float* out = (float*)d_out;

    float*  wsf  = (float*)d_ws;
    float*  dsum = wsf;                         // [64]
    float*  u    = wsf + 64;                    // [BB]
    float*  v    = wsf + 64 + BB;               // [NN]
    __half* Kh   = (__half*)(wsf + 64 + BB + NN);   // [BB*NN] fp16 = 33.5 MB
    float*  partA = (float*)d_out;              // [64*4096] = 1 MB
    float*  partB = partA + NSL * NN;           // [64*4096] = 1 MB; dead before k_P

    (void)hipMemsetAsync(dsum, 0, sizeof(float), stream);
    k_mean<<<2048, 256, 0, stream>>>(Dt, dsum, partA, cap);
    k_K<<<BB / RPB, 256, 0, stream>>>(users, pois, Dt, poi_emb, user_emb, dsum, Kh);
    for (int it = 0; it < 10; it++) {
        const float* pin  = (it & 1) ? partB : partA;
        float*       pout = (it & 1) ? partA : partB;
        k_it<<<IBLK, 512, 0, stream>>>(Kh, cap, pin, pout, u);
    }
    k_fin<<<NN / 512, 512, 0, stream>>>(partA, cap, v);   // it=9 wrote partA
    k_P<<<PBLK, 256, 0, stream>>>(Kh, u, v, out);
}

// Round 13
// 371.965 us; speedup vs baseline: 9.3933x; 1.5020x over previous
//
#include <hip/hip_runtime.h>
#include <hip/hip_fp16.h>

#define BB 4096
#define NN 4096
#define RPB 4            // rows per block in k_K
#define RPI 8            // rows per block in k_it / k_P
#define NBLK (BB / RPI)  // 512 row-blocks
#define NTSLOT 60        // slots >= NTSLOT use nt K loads (keep 480 rows/XCD in L2)

// XCD-contiguous swizzles (round-robin dispatch: bid%8 -> XCD bid%8).
// XCD x owns K rows [512x, 512x+512) in ALL kernels (producer + consumers).
__device__ __forceinline__ int swzK(int bid) { return (bid & 7) * 128 + (bid >> 3); } // 1024 blk

// non-temporal helpers via native clang vector types (HIP_vector_type is
// rejected by __builtin_nontemporal_*)
typedef float vf4 __attribute__((ext_vector_type(4)));
typedef int   vi4 __attribute__((ext_vector_type(4)));
__device__ __forceinline__ float4 ntl4(const float4* p) {
    vf4 r = __builtin_nontemporal_load((const vf4*)p);
    return *(float4*)&r;
}
__device__ __forceinline__ int4 ntl4i(const int4* p) {
    vi4 r = __builtin_nontemporal_load((const vi4*)p);
    return *(int4*)&r;
}
__device__ __forceinline__ void nts4(float4* p, float4 v) {
    __builtin_nontemporal_store(*(vf4*)&v, (vf4*)p);
}

// ---------------- mean(D) reduction + v=1 init ----------------
__global__ __launch_bounds__(256) void k_mean(
        const float* __restrict__ Dt, float* __restrict__ dsum,
        float* __restrict__ v) {
    const int tid = blockIdx.x * blockDim.x + threadIdx.x;
    const int gs = gridDim.x * blockDim.x;
    if (tid < NN) v[tid] = 1.0f;
    const float4* D4 = (const float4*)Dt;
    const int total4 = (BB * NN) / 4;
    float s = 0.f;
    for (int i = tid; i < total4; i += gs) {
        float4 d = ntl4(&D4[i]);
        s += (d.x + d.y) + (d.z + d.w);
    }
    #pragma unroll
    for (int off = 32; off > 0; off >>= 1) s += __shfl_down(s, off, 64);
    __shared__ float ls[4];
    if ((threadIdx.x & 63) == 0) ls[threadIdx.x >> 6] = s;
    __syncthreads();
    if (threadIdx.x == 0) atomicAdd(dsum, (ls[0] + ls[1]) + (ls[2] + ls[3]));
}

// ---------------- K = exp(5*dot - 5*D/mean), fp16, fp16 lut ----------------
// XCD-panel swizzle: each XCD writes its own K panel (stays in its L2).
// pois/Dt are one-touch -> nt loads (don't evict panel or poi_emb).
__global__ __launch_bounds__(256) void k_K(
        const int* __restrict__ users, const int* __restrict__ pois,
        const float* __restrict__ Dt, const float* __restrict__ poi_emb,
        const float* __restrict__ user_emb, const float* __restrict__ dsum,
        __half* __restrict__ K) {
    __shared__ __half slut[RPB][NN];      // 32 KB
    __shared__ float ues[RPB * 16];
    const int t = threadIdx.x;
    const int b0 = swzK(blockIdx.x) * RPB;
    if (t < RPB * 16) {
        int r = t >> 4, d = t & 15;
        ues[t] = user_emb[(size_t)users[b0 + r] * 16 + d];
    }
    __syncthreads();
    float ue[RPB][16];
    #pragma unroll
    for (int r = 0; r < RPB; r++)
        #pragma unroll
        for (int d = 0; d < 16; d++) ue[r][d] = ues[r * 16 + d];

    const float4* pe4 = (const float4*)poi_emb;
    for (int j = t; j < NN; j += 256) {
        float4 p0 = pe4[j * 4 + 0];
        float4 p1 = pe4[j * 4 + 1];
        float4 p2 = pe4[j * 4 + 2];
        float4 p3 = pe4[j * 4 + 3];
        #pragma unroll
        for (int r = 0; r < RPB; r++) {
            float acc = p0.x*ue[r][0]  + p0.y*ue[r][1]  + p0.z*ue[r][2]  + p0.w*ue[r][3]
                      + p1.x*ue[r][4]  + p1.y*ue[r][5]  + p1.z*ue[r][6]  + p1.w*ue[r][7]
                      + p2.x*ue[r][8]  + p2.y*ue[r][9]  + p2.z*ue[r][10] + p2.w*ue[r][11]
                      + p3.x*ue[r][12] + p3.y*ue[r][13] + p3.z*ue[r][14] + p3.w*ue[r][15];
            slut[r][j] = __float2half(acc);
        }
    }
    __syncthreads();                       // lut read-only from here on
    const float cc = 5.0f * 16777216.0f / dsum[0];   // 5 / mean(D)
    #pragma unroll
    for (int r = 0; r < RPB; r++) {
        const size_t base = (size_t)(b0 + r) * NN;
        const int4*   p4 = (const int4*)(pois + base);
        const float4* d4 = (const float4*)(Dt + base);
        #pragma unroll
        for (int i = 0; i < NN / 4 / 256; i++) {     // 4
            const int q = t + i * 256;
            int4   ci = ntl4i(&p4[q]);
            float4 cd = ntl4(&d4[q]);
            float k0 = __expf(5.0f * __half2float(slut[r][ci.x]) - cc * cd.x);
            float k1 = __expf(5.0f * __half2float(slut[r][ci.y]) - cc * cd.y);
            float k2 = __expf(5.0f * __half2float(slut[r][ci.z]) - cc * cd.z);
            float k3 = __expf(5.0f * __half2float(slut[r][ci.w]) - cc * cd.w);
            __half2* kw = (__half2*)&K[base + 4 * (size_t)q];
            kw[0] = __floats2half2_rn(k0, k1);
            kw[1] = __floats2half2_rn(k2, k3);
        }
    }
}

// ---------------- fused sinkhorn iteration (512x512, panel-L2-aware) -------
// Thread t owns cols [8t, 8t+8). Slots >= NTSLOT stream K via nt (their rows
// are the sacrificial 32/512 per XCD that keep the other 480 L2-resident).
// Partials are one-touch -> nt stores.
__global__ __launch_bounds__(512) void k_it(
        const __half* __restrict__ K, const float* __restrict__ v,
        float* __restrict__ part, float* __restrict__ u) {
    const int t = threadIdx.x;            // 0..511
    const int slot = blockIdx.x >> 3;
    const int sb = (blockIdx.x & 7) * 64 + slot;
    const int r0 = sb * RPI;
    const bool nt = (slot >= NTSLOT);

    const float4* w4 = (const float4*)v;
    float4 w0 = w4[2 * t], w1 = w4[2 * t + 1];

    float4 h[RPI];
    #pragma unroll
    for (int r = 0; r < RPI; r++) {
        const float4* p = (const float4*)(K + (size_t)(r0 + r) * NN) + t;
        h[r] = nt ? ntl4(p) : *p;
    }

    float acc[RPI];
    #pragma unroll
    for (int r = 0; r < RPI; r++) {
        const __half2* a = (const __half2*)&h[r];
        float2 f; float s = 0.f;
        f = __half22float2(a[0]); s += f.x * w0.x + f.y * w0.y;
        f = __half22float2(a[1]); s += f.x * w0.z + f.y * w0.w;
        f = __half22float2(a[2]); s += f.x * w1.x + f.y * w1.y;
        f = __half22float2(a[3]); s += f.x * w1.z + f.y * w1.w;
        acc[r] = s;
    }
    #pragma unroll
    for (int off = 32; off > 0; off >>= 1)
        #pragma unroll
        for (int r = 0; r < RPI; r++) acc[r] += __shfl_down(acc[r], off, 64);
    __shared__ float ls[8][RPI];
    __shared__ float us[RPI];
    if ((t & 63) == 0)
        #pragma unroll
        for (int r = 0; r < RPI; r++) ls[t >> 6][r] = acc[r];
    __syncthreads();
    if (t < RPI) {
        float s = 0.f;
        #pragma unroll
        for (int wv = 0; wv < 8; wv++) s += ls[wv][t];
        float uu = 1.0f / s;
        us[t] = uu;
        u[r0 + t] = uu;
    }
    __syncthreads();

    // column partials over this block's rows (registers only)
    float4 A0 = make_float4(0, 0, 0, 0), A1 = A0;
    #pragma unroll
    for (int r = 0; r < RPI; r++) {
        const float ur = us[r];
        const __half2* a = (const __half2*)&h[r];
        float2 f;
        f = __half22float2(a[0]); A0.x += ur * f.x; A0.y += ur * f.y;
        f = __half22float2(a[1]); A0.z += ur * f.x; A0.w += ur * f.y;
        f = __half22float2(a[2]); A1.x += ur * f.x; A1.y += ur * f.y;
        f = __half22float2(a[3]); A1.z += ur * f.x; A1.w += ur * f.y;
    }
    float4* p4 = (float4*)(part + (size_t)sb * NN);
    nts4(&p4[2 * t],     A0);
    nts4(&p4[2 * t + 1], A1);
}

// ---------------- v[n] = cap[n] / sum_sb part[sb][n] ----------------
__global__ __launch_bounds__(256) void k_red(
        const float* __restrict__ part, const float* __restrict__ cap,
        float* __restrict__ v) {
    const int t = threadIdx.x;
    const int g = blockIdx.x;
    const int j = t & 7;
    const int s = t >> 3;
    const float4* p4 = (const float4*)part;
    float4 a = make_float4(0, 0, 0, 0);
    #pragma unroll
    for (int i = 0; i < NBLK / 32; i++) {
        float4 x = ntl4(&p4[(size_t)(s + 32 * i) * (NN / 4) + g * 8 + j]);
        a.x += x.x; a.y += x.y; a.z += x.z; a.w += x.w;
    }
    __shared__ float4 red[32][8];
    red[s][j] = a;
    __syncthreads();
    if (t < 8) {
        float4 b = red[0][t];
        #pragma unroll
        for (int s2 = 1; s2 < 32; s2++) {
            float4 x = red[s2][t];
            b.x += x.x; b.y += x.y; b.z += x.z; b.w += x.w;
        }
        float4 cc = ((const float4*)cap)[g * 8 + t];
        ((float4*)v)[g * 8 + t] =
            make_float4(cc.x / b.x, cc.y / b.y, cc.z / b.z, cc.w / b.w);
    }
}

// ---------------- P = K * u[b] * v[n]: panel-L2 reads, nt writes ----------
__global__ __launch_bounds__(256) void k_P(
        const __half* __restrict__ K, const float* __restrict__ u,
        const float* __restrict__ v, float* __restrict__ P) {
    const int t = threadIdx.x;
    const int slot = blockIdx.x >> 3;
    const int sb = (blockIdx.x & 7) * 64 + slot;
    const int r0 = sb * RPI;
    const bool nt = (slot >= NTSLOT);
    const float4* v4 = (const float4*)v;
    float4 va0 = v4[2 * t],       va1 = v4[2 * t + 1];
    float4 vb0 = v4[512 + 2 * t], vb1 = v4[512 + 2 * t + 1];
    #pragma unroll 2
    for (int r = 0; r < RPI; r++) {
        const int b = r0 + r;
        const float ub = u[b];
        const size_t base = (size_t)b * NN;
        const float4* k4 = (const float4*)(K + base);
        float4 raw0 = nt ? ntl4(&k4[t])       : k4[t];
        float4 raw1 = nt ? ntl4(&k4[256 + t]) : k4[256 + t];
        const __half2* ha = (const __half2*)&raw0;
        const __half2* hb = (const __half2*)&raw1;
        float2 f0 = __half22float2(ha[0]);
        float2 f1 = __half22float2(ha[1]);
        float2 f2 = __half22float2(ha[2]);
        float2 f3 = __half22float2(ha[3]);
        float2 g0 = __half22float2(hb[0]);
        float2 g1 = __half22float2(hb[1]);
        float2 g2 = __half22float2(hb[2]);
        float2 g3 = __half22float2(hb[3]);
        float4* P4 = (float4*)(P + base);
        nts4(&P4[2*t],       make_float4(f0.x*ub*va0.x, f0.y*ub*va0.y, f1.x*ub*va0.z, f1.y*ub*va0.w));
        nts4(&P4[2*t+1],     make_float4(f2.x*ub*va1.x, f2.y*ub*va1.y, f3.x*ub*va1.z, f3.y*ub*va1.w));
        nts4(&P4[512+2*t],   make_float4(g0.x*ub*vb0.x, g0.y*ub*vb0.y, g1.x*ub*vb0.z, g1.y*ub*vb0.w));
        nts4(&P4[512+2*t+1], make_float4(g2.x*ub*vb1.x, g2.y*ub*vb1.y, g3.x*ub*vb1.z, g3.y*ub*vb1.w));
    }
}

extern "C" void kernel_launch(void* const* d_in, const int* in_sizes, int n_in,
                              void* d_out, int out_size, void* d_ws, size_t ws_size,
                              hipStream_t stream) {
    const int*   users    = (const int*)d_in[0];
    const int*   pois     = (const int*)d_in[1];
    const float* Dt       = (const float*)d_in[2];
    const float* poi_emb  = (const float*)d_in[3];
    const float* user_emb = (const float*)d_in[4];
    const float* cap      = (const float*)d_in[5];
    float* out = (float*)d_out;

    float*  wsf  = (float*)d_ws;
    float*  dsum = wsf;                         // [64]
    float*  u    = wsf + 64;                    // [BB]
    float*  v    = wsf + 64 + BB;               // [NN]
    __half* Kh   = (__half*)(wsf + 64 + BB + NN);   // [BB*NN] fp16 = 33.5 MB
    float*  part = (float*)d_out;               // [NBLK*NN] = 8 MB; dead before k_P

    (void)hipMemsetAsync(dsum, 0, sizeof(float), stream);
    k_mean<<<2048, 256, 0, stream>>>(Dt, dsum, v);
    k_K<<<BB / RPB, 256, 0, stream>>>(users, pois, Dt, poi_emb, user_emb, dsum, Kh);
    for (int it = 0; it < 10; it++) {
        k_it<<<NBLK, 512, 0, stream>>>(Kh, v, part, u);
        k_red<<<128, 256, 0, stream>>>(part, cap, v);
    }
    k_P<<<NBLK, 256, 0, stream>>>(Kh, u, v, out);
}